// Round 4
// baseline (342.108 us; speedup 1.0000x reference)
//
#include <hip/hip_runtime.h>

// PWLU (channelwise piecewise-linear unit), non-learnable bounds ±2.3.
// x: [B=64, C=256, H=56, W=56] fp32; points: [C,7]; left/right_diffs: [C].
// out[i] = false_points[c, r] + (xn - r) * dists  with per-region (fp, slope).
//
// R5 post-mortem: wave-local table + no barrier + store burst = 326.8us
// total, kernel ~76us @ 5.37 TB/s -- identical to R2/R4. Eliminated:
// block structure, table build, barrier drain, vmcnt queue order.
// R6 theory: the one factor common to ALL versions is the nontemporal
// hint. nt bypasses TCC(L2) allocation; plain streams get line-granular
// aggregation at the HBM interface (the 6.5 TB/s fills and the 6.29 TB/s
// m13 copy ceiling are both PLAIN accesses). L2 pollution is irrelevant
// here (pure streaming), so plain has no downside. Single-variable A/B:
// R5 exactly, nt removed.

constexpr int NP   = 7;          // n_points
constexpr int HW   = 56 * 56;    // 3136 floats per (b,c) plane
constexpr int HW4  = HW / 4;     // 784 f4 per plane
constexpr int K    = 8;          // f4 per thread
constexpr int F4PB = 256 * K;    // 2048 f4 per block (6272 blocks exact)

typedef float f4 __attribute__((ext_vector_type(4)));

__device__ __forceinline__ float pwlu1(float xv, const float2* __restrict__ tc) {
    constexpr float sim_left = -3.0666666666666664f;   // -2.3 - 4.6/6
    constexpr float inv_len  = 1.3043478260869565f;    // 6/4.6
    constexpr float hi       = 7.007f;                  // (n_regions+1)*1.001
    const float xn = (xv - sim_left) * inv_len;
    const int   r  = (int)fminf(fmaxf(xn, 0.0f), hi);
    const float2 t = tc[r];
    return fmaf(xn - (float)r, t.y, t.x);
}

__device__ __forceinline__ f4 pwlu4(f4 v, const float2* __restrict__ tc) {
    f4 o;
    o.x = pwlu1(v.x, tc);
    o.y = pwlu1(v.y, tc);
    o.z = pwlu1(v.z, tc);
    o.w = pwlu1(v.w, tc);
    return o;
}

__global__ __launch_bounds__(256) void pwlu_kernel(
    const f4* __restrict__ x,
    const float* __restrict__ points,
    const float* __restrict__ left_diffs,
    const float* __restrict__ right_diffs,
    f4* __restrict__ out)
{
    // Per-WAVE table copies: wave w owns tbl[w][rel*8 + r], rel = plane - plane_lo.
    // Producer and consumer are the same wave -> in-wave lgkmcnt ordering only,
    // no s_barrier anywhere.
    __shared__ float2 tbl[4][32];

    const int tid  = threadIdx.x;
    const int wv   = tid >> 6;
    const int lane = tid & 63;
    const unsigned base = (unsigned)blockIdx.x * F4PB;

    // All 8 streaming loads in flight before/during the table build.
    const f4* __restrict__ xp = x + base + tid;
    f4 v[K];
#pragma unroll
    for (int j = 0; j < K; ++j)
        v[j] = xp[j * 256];

    const unsigned plane_lo = base / 784u;   // wave-uniform

    float2* __restrict__ wt = &tbl[wv][0];
    if (lane < 32) {
        const int rel = lane >> 3;           // straddled plane 0..3
        const int r   = lane & 7;            // region entry 0..7
        const int c   = (int)((plane_lo + rel) & 255u);
        const float* p = points + c * NP;
        float fp, df;
        if (r == 0)       { const float ld = left_diffs[c]; fp = p[0] - ld;  df = ld; }
        else if (r == NP) { fp = p[NP - 1];                  df = right_diffs[c]; }
        else              { const float a = p[r - 1], b = p[r]; fp = a; df = b - a; }
        wt[lane] = make_float2(fp, df);
    }
    __builtin_amdgcn_wave_barrier();   // scheduling fence only (no s_barrier)

    // Consume loads in issue order; results overwrite v[] in place.
#pragma unroll
    for (int j = 0; j < K; ++j) {
        const unsigned idx = base + j * 256u + (unsigned)tid;   // < 2^24
        const int rel = (int)(idx / 784u - plane_lo);           // magic-mul
        v[j] = pwlu4(v[j], wt + (rel << 3));
    }

    // Store burst at the end.
    f4* __restrict__ op = out + base + tid;
#pragma unroll
    for (int j = 0; j < K; ++j)
        op[j * 256] = v[j];
}

extern "C" void kernel_launch(void* const* d_in, const int* in_sizes, int n_in,
                              void* d_out, int out_size, void* d_ws, size_t ws_size,
                              hipStream_t stream) {
    const f4*    x  = (const f4*)d_in[0];
    const float* pt = (const float*)d_in[1];
    const float* ld = (const float*)d_in[2];
    const float* rd = (const float*)d_in[3];
    f4*          o  = (f4*)d_out;

    const int planes = in_sizes[0] / HW;            // B*C = 16384
    const int blocks = planes * HW4 / F4PB;         // 6272, exact
    pwlu_kernel<<<blocks, 256, 0, stream>>>(x, pt, ld, rd, o);
}

// Round 6
// 326.125 us; speedup vs baseline: 1.0490x; 1.0490x over previous
//
#include <hip/hip_runtime.h>

// PWLU (channelwise piecewise-linear unit), non-learnable bounds ±2.3.
// x: [B=64, C=256, H=56, W=56] fp32; points: [C,7]; left/right_diffs: [C].
// out[i] = false_points[c, r] + (xn - r) * diffs[c, r]
//   xn = (x - sim_left) / region_len,  r = int(clip(xn, 0, 7.007))
//
// FINAL (R7 = revert to R2, the best harness-verified version: 324.3 us).
// R8: resubmission of R7 unchanged — R7's bench was an infra failure
// (container acquisition), no GPU evidence produced.
// Elimination matrix across R3-R6:
//   - block granularity (per-plane / 16-plane / plane-agnostic): null (~76us)
//   - table build shape (8-entry / 256-ch / wave-local): null
//   - barrier drain + store-queue order (no-barrier + store burst): null
//   - nontemporal vs plain (R6): nt WINS by ~15% (kernel 76 -> 88 us plain)
// Kernel ~75us = 411 MB @ ~5.5 TB/s mixed r/w; VALUBusy ~5%, LDS conflicts 0,
// occupancy-shape invariant. Remaining gap to 6.29 TB/s pure-copy ubench is
// mixed-stream HBM efficiency, not source-addressable. Total bench time is
// dominated by 2x ~125us harness 0xAA re-poison fills (822 MB each).

constexpr int NP  = 7;        // n_points
constexpr int NT  = 8;        // table entries = n_points + 1
constexpr int CH  = 256;      // channels
constexpr int HW  = 56 * 56;  // 3136 elements per (b,c) plane
constexpr int HW4 = HW / 4;   // 784 float4 per plane = 3*256 + 16

typedef float f4 __attribute__((ext_vector_type(4)));

__device__ __forceinline__ float pwlu1(float xv, const float2* tbl,
                                       float sim_left, float inv_len, float hi) {
    const float xn = (xv - sim_left) * inv_len;
    const int   r  = (int)fminf(fmaxf(xn, 0.0f), hi);
    const float2 t = tbl[r];
    return fmaf(xn - (float)r, t.y, t.x);
}

__device__ __forceinline__ f4 pwlu4(f4 v, const float2* tbl,
                                    float sim_left, float inv_len, float hi) {
    f4 o;
    o.x = pwlu1(v.x, tbl, sim_left, inv_len, hi);
    o.y = pwlu1(v.y, tbl, sim_left, inv_len, hi);
    o.z = pwlu1(v.z, tbl, sim_left, inv_len, hi);
    o.w = pwlu1(v.w, tbl, sim_left, inv_len, hi);
    return o;
}

__global__ __launch_bounds__(256) void pwlu_kernel(
    const f4* __restrict__ x,
    const float* __restrict__ points,
    const float* __restrict__ left_diffs,
    const float* __restrict__ right_diffs,
    f4* __restrict__ out)
{
    __shared__ float2 tbl[NT];   // (false_point, slope) per region

    const int plane = blockIdx.x;        // b*C + c
    const int c     = plane & (CH - 1);
    const int tid   = threadIdx.x;
    const size_t base = (size_t)plane * HW4;

    // Issue the plane loads first: global latency overlaps table build+barrier.
    const f4* __restrict__ xp = x + base + tid;
    f4 v0 = __builtin_nontemporal_load(xp);
    f4 v1 = __builtin_nontemporal_load(xp + 256);
    f4 v2 = __builtin_nontemporal_load(xp + 512);
    const bool tail = tid < (HW4 - 3 * 256);   // 16 threads
    f4 v3;
    if (tail) v3 = __builtin_nontemporal_load(xp + 768);

    if (tid < NT) {
        const int r = tid;
        const float* p = points + c * NP;
        float fp, df;
        if (r == 0) {
            const float ld = left_diffs[c];
            fp = p[0] - ld; df = ld;
        } else if (r == NP) {
            fp = p[NP - 1]; df = right_diffs[c];
        } else {
            const float a = p[r - 1], b = p[r];
            fp = a; df = b - a;
        }
        tbl[r] = make_float2(fp, df);
    }
    __syncthreads();

    const float sim_left = -3.0666666666666664f;   // -2.3 - 4.6/6
    const float inv_len  = 1.3043478260869565f;    // 6/4.6
    const float hi       = 7.007f;                  // (n_regions+1)*1.001

    f4* __restrict__ op = out + base + tid;
    __builtin_nontemporal_store(pwlu4(v0, tbl, sim_left, inv_len, hi), op);
    __builtin_nontemporal_store(pwlu4(v1, tbl, sim_left, inv_len, hi), op + 256);
    __builtin_nontemporal_store(pwlu4(v2, tbl, sim_left, inv_len, hi), op + 512);
    if (tail)
        __builtin_nontemporal_store(pwlu4(v3, tbl, sim_left, inv_len, hi), op + 768);
}

extern "C" void kernel_launch(void* const* d_in, const int* in_sizes, int n_in,
                              void* d_out, int out_size, void* d_ws, size_t ws_size,
                              hipStream_t stream) {
    const f4*    x  = (const f4*)d_in[0];
    const float* pt = (const float*)d_in[1];
    const float* ld = (const float*)d_in[2];
    const float* rd = (const float*)d_in[3];
    f4*          o  = (f4*)d_out;

    const int planes = in_sizes[0] / HW;   // B*C = 16384
    pwlu_kernel<<<planes, 256, 0, stream>>>(x, pt, ld, rd, o);
}